// Round 5
// baseline (1595.682 us; speedup 1.0000x reference)
//
#include <hip/hip_runtime.h>
#include <hip/hip_bf16.h>
#include <math.h>

// FADiTBlockS2: b=4, nlat=128, nlon=256, dim=256, H=8, DH=64, BNECK=128, NK=32
// Round 9: k_ffn4 (354us) was LDS-read-issue-bound: 4 waves read IDENTICAL
// weight addresses (33 b128/wave/chunk, ~3200 cyc/chunk vs 155 cyc MFMA).
// k_ffn5 = 2 token-sets per wave (32 tok/wave, 128/block, grid 1024): each
// weight b128 now feeds 2 MFMAs -> LDS reads/token halve. VGPR ~230, lb(256,2).
// k_qkT2 = LDS tile transpose (old k_qkT read 1 float per 64B line).

#define B_ 4
#define NLAT 128
#define NLON 256
#define NTOK (B_*NLAT*NLON)   // 131072
#define SLOT_ELE ((size_t)16777216)   // per-b slot elements (8h x 32768tok x 64c)

typedef __hip_bfloat16 bf16;
typedef unsigned short u16;
typedef __attribute__((ext_vector_type(8))) short short8;
typedef __attribute__((ext_vector_type(4))) float f32x4;

__device__ __forceinline__ float b2f(bf16 x){ return __bfloat162float(x); }
__device__ __forceinline__ bf16  f2b(float x){ return __float2bfloat16(x); }
__device__ __forceinline__ u16 f2bits(float x){
  bf16 h = __float2bfloat16(x); return *(u16*)&h;
}
__device__ __forceinline__ float bits2f(u16 u){
  union { unsigned int i; float f; } v; v.i = ((unsigned int)u) << 16; return v.f;
}
__device__ __forceinline__ float gelu_f(float x){
  float x3 = x*x*x;
  return 0.5f*x*(1.0f + tanhf(0.7978845608028654f*(x + 0.044715f*x3)));
}
// identity-exact fast gelu: tanh(t) = 1 - 2/(exp2(t*2/ln2)+1)
__device__ __forceinline__ float gelu_fast(float x){
  float t = 0.7978845608028654f*(x + 0.044715f*x*x*x);
  float e = __builtin_amdgcn_exp2f(t * 2.8853900817779268f);
  return x - x*__builtin_amdgcn_rcpf(e + 1.0f);
}
__device__ __forceinline__ float ldin(const void* p, size_t i, int flag){
  return flag ? b2f(((const bf16*)p)[i]) : ((const float*)p)[i];
}
__device__ __forceinline__ short4 pack4(float a, float b, float c, float d){
  short4 r; r.x = (short)f2bits(a); r.y = (short)f2bits(b);
  r.z = (short)f2bits(c); r.w = (short)f2bits(d); return r;
}
__device__ __forceinline__ short8 pack8(float a, float b, float c, float d,
                                        float e, float f, float g, float h){
  short8 r;
  r[0]=(short)f2bits(a); r[1]=(short)f2bits(b); r[2]=(short)f2bits(c); r[3]=(short)f2bits(d);
  r[4]=(short)f2bits(e); r[5]=(short)f2bits(f); r[6]=(short)f2bits(g); r[7]=(short)f2bits(h);
  return r;
}
// async global->LDS 16B: lds dest is wave-uniform base (+lane*16 by HW),
// global src is per-lane.
__device__ __forceinline__ void stage16(const u16* g, u16* l){
  __builtin_amdgcn_global_load_lds(
      (const __attribute__((address_space(1))) void*)g,
      (__attribute__((address_space(3))) void*)l, 16, 0, 0);
}

// ---------------- dtype detection: lon_diff[1] == 2*pi/256 -----------------
__global__ void k_detect(const void* lon_diff, int* flag){
  const float c = 0.02454369260617026f;
  float asF = ((const float*)lon_diff)[1];
  float asB = b2f(((const bf16*)lon_diff)[1]);
  float ef = fabsf(asF - c), eb = fabsf(asB - c);
  if (!isfinite(ef)) ef = 1e30f;
  *flag = (eb < ef) ? 1 : 0;   // 1 = bf16 buffers, 0 = f32 buffers
}

// ---------------- all-input convert in one launch --------------------------
struct CvtTab {
  const void* src[27];
  float* dst[27];
  int cum[28];
};
__global__ __launch_bounds__(256) void k_cvtall(CvtTab t, const int* __restrict__ flag,
                                                int total){
  int f = *flag;
  for (int i = blockIdx.x*256 + threadIdx.x; i < total; i += gridDim.x*256){
    int s = 0;
    while (i >= t.cum[s+1]) ++s;
    int off = i - t.cum[s];
    t.dst[s][off] = ldin(t.src[s], off, f);
  }
}

// ------- pack weight [K][N] f32 -> fragment-order bf16 ([nt][ks][lane][8]) -
__global__ __launch_bounds__(256) void k_wprep(const float* __restrict__ W,
                                               u16* __restrict__ wf,
                                               int KS, int ldn, int total){
  int gid = blockIdx.x*256 + threadIdx.x;
  if (gid >= total) return;
  int j = gid & 7; int lane = (gid >> 3) & 63; int rest = gid >> 9;
  int ks = rest % KS; int nt = rest / KS;
  int k = ks*32 + (lane >> 4)*8 + j;
  int n = nt*16 + (lane & 15);
  wf[gid] = f2bits(W[(size_t)k*ldn + n]);
}

// ------- w2 pack: [ksAll 0..31][nt 0..15][lane][8]; W2 is [1024][256] ------
__global__ __launch_bounds__(256) void k_wprep2(const float* __restrict__ W,
                                                u16* __restrict__ wf){
  int gid = blockIdx.x*256 + threadIdx.x;   // 262144 total
  int j = gid & 7; int lane = (gid >> 3) & 63; int rest = gid >> 9;
  int nt = rest & 15; int ksAll = rest >> 4;
  int k = ksAll*32 + (lane >> 4)*8 + j;
  int n = nt*16 + (lane & 15);
  wf[gid] = f2bits(W[(size_t)k*256 + n]);
}

// ------- transposed bf16 copy: WT[n][k] = W[k][n] ---------------------------
__global__ __launch_bounds__(256) void k_wtrans(const float* __restrict__ W,
                                                u16* __restrict__ WT, int K, int N){
  int gid = blockIdx.x*256 + threadIdx.x;
  if (gid >= K*N) return;
  int k = gid % K, n = gid / K;
  WT[(size_t)n*K + k] = f2bits(W[(size_t)k*N + n]);
}

// ---------------- mod = scalar_cond @ adaLN_w + adaLN_b  (4 x 1536) --------
__global__ __launch_bounds__(256) void k_mod(const float* __restrict__ sc,
                                             const float* __restrict__ w,
                                             const float* __restrict__ bias,
                                             float* __restrict__ mod){
  int gid = blockIdx.x*256 + threadIdx.x;
  int s = gid / 1536, j = gid % 1536;
  float acc = bias[j];
  for (int c = 0; c < 256; ++c) acc += sc[s*256+c] * w[c*1536+j];
  mod[gid] = acc;
}

// ---------------- lw = cos(lat)/mean(cos(lat)) -----------------------------
__global__ __launch_bounds__(128) void k_lw(const float* __restrict__ lat,
                                            float* __restrict__ lw){
  __shared__ float red[128];
  int i = threadIdx.x;
  float cv = cosf(lat[i]);
  red[i] = cv; __syncthreads();
  for (int s = 64; s > 0; s >>= 1){ if (i < s) red[i] += red[i+s]; __syncthreads(); }
  float mean = red[0] * (1.0f/128.0f);
  lw[i] = cv / mean;
}

// ------- um = LN(u)*(1+sc_msa)+sh_msa : 64 tokens/block, coalesced ---------
__global__ __launch_bounds__(256) void k_um2(const void* __restrict__ u,
                                             const float* __restrict__ mod,
                                             u16* __restrict__ um,
                                             const int* __restrict__ flag){
  __shared__ u16 tile[64][264];
  __shared__ float r1[64][4], r2[64][4], mv[64], rs[64];
  __shared__ float ssh[256], ssc[256];
  int f = *flag; int tid = threadIdx.x;
  int t0 = blockIdx.x*64; int b = t0 >> 15;
  ssh[tid] = mod[b*1536 + tid];
  ssc[tid] = mod[b*1536 + 256 + tid];
  // phase 1: coalesced load -> bf16 tile
  for (int it = 0; it < 16; ++it){
    int idx = it*256 + tid;       // 4096 vec4 groups
    int tok = idx >> 6, c4 = idx & 63;
    short4 v4;
    if (f){
      v4 = *(const short4*)((const bf16*)u + ((size_t)(t0+tok))*256 + c4*4);
    } else {
      float4 fv = ((const float4*)u)[((size_t)(t0+tok))*64 + c4];
      v4 = pack4(fv.x, fv.y, fv.z, fv.w);
    }
    *(short4*)&tile[tok][c4*4] = v4;
  }
  __syncthreads();
  // phase 2: stats (4 threads per token)
  {
    int tok = tid >> 2, part = tid & 3;
    float s1 = 0.f, s2 = 0.f;
    for (int c4 = 0; c4 < 16; ++c4){
      short4 v4 = *(const short4*)&tile[tok][part*64 + c4*4];
      float a = bits2f((u16)v4.x), bb = bits2f((u16)v4.y),
            c = bits2f((u16)v4.z), d = bits2f((u16)v4.w);
      s1 += a+bb+c+d; s2 += a*a+bb*bb+c*c+d*d;
    }
    r1[tok][part] = s1; r2[tok][part] = s2;
  }
  __syncthreads();
  if ((tid & 3) == 0){
    int tok = tid >> 2;
    float a1 = r1[tok][0]+r1[tok][1]+r1[tok][2]+r1[tok][3];
    float a2 = r2[tok][0]+r2[tok][1]+r2[tok][2]+r2[tok][3];
    float mean = a1*(1.0f/256.0f);
    float var = a2*(1.0f/256.0f) - mean*mean;
    mv[tok] = mean; rs[tok] = rsqrtf(var + 1e-5f);
  }
  __syncthreads();
  // phase 3: modulate + coalesced store
  for (int it = 0; it < 16; ++it){
    int idx = it*256 + tid;
    int tok = idx >> 6, c4 = idx & 63;
    float mean = mv[tok], rstd = rs[tok];
    short4 v4 = *(const short4*)&tile[tok][c4*4];
    float y[4]; u16 raw[4] = {(u16)v4.x,(u16)v4.y,(u16)v4.z,(u16)v4.w};
    #pragma unroll
    for (int p = 0; p < 4; ++p){
      int c = c4*4 + p;
      y[p] = (bits2f(raw[p]) - mean)*rstd*(1.0f + ssc[c]) + ssh[c];
    }
    *(short4*)(um + ((size_t)(t0+tok))*256 + c4*4) = pack4(y[0],y[1],y[2],y[3]);
  }
}

// ---------------- redx[b,l,c] = (1/128) * sum_i um[b,i,l,c]*lw[i] ----------
__global__ __launch_bounds__(256) void k_redx(const u16* __restrict__ um,
                                              const float* __restrict__ lw,
                                              float* __restrict__ redx){
  __shared__ float lws[128];
  int tid = threadIdx.x;
  if (tid < 128) lws[tid] = lw[tid];
  __syncthreads();
  int gid = blockIdx.x*256 + tid;
  int c = gid & 255; int l = (gid >> 8) & 255; int b = gid >> 16;
  float acc = 0.0f;
  for (int i = 0; i < 128; ++i)
    acc += bits2f(um[(((size_t)(b*128 + i)*256 + l)*256) + c]) * lws[i];
  redx[gid] = acc * (1.0f/128.0f);
}

__global__ __launch_bounds__(256) void k_redy(const u16* __restrict__ um,
                                              float* __restrict__ redy){
  int gid = blockIdx.x*256 + threadIdx.x;
  int c = gid & 255; int i = (gid >> 8) & 127; int b = gid >> 15;
  float acc = 0.0f;
  for (int l = 0; l < 256; ++l)
    acc += bits2f(um[(((size_t)(b*128 + i)*256 + l)*256) + c]);
  redy[gid] = acc * (1.0f/256.0f);
}

// ------- dual row GEMM: x-chain rows [0,nbx), y-chain rows [nbx,nbx+nby) ---
__global__ __launch_bounds__(256) void gemm_row2(
    const float* __restrict__ Ax, const float* __restrict__ Wx,
    const float* __restrict__ bx, float* __restrict__ Cx, int Kx, int Nx,
    const float* __restrict__ Ay, const float* __restrict__ Wy,
    const float* __restrict__ by, float* __restrict__ Cy, int Ky, int Ny,
    int nbx, int act){
  __shared__ float As[256];
  int bid = blockIdx.x; int tid = threadIdx.x;
  const float* A; const float* W; const float* bias; float* C; int K, N, r;
  if (bid < nbx){ A=Ax; W=Wx; bias=bx; C=Cx; K=Kx; N=Nx; r=bid; }
  else          { A=Ay; W=Wy; bias=by; C=Cy; K=Ky; N=Ny; r=bid-nbx; }
  for (int k = tid; k < K; k += 256) As[k] = A[(size_t)r*K + k];
  __syncthreads();
  for (int n = tid; n < N; n += 256){
    float a0=0.f, a1=0.f, a2=0.f, a3=0.f;
    for (int k = 0; k < K; k += 4){
      a0 += As[k+0]*W[(size_t)(k+0)*N + n];
      a1 += As[k+1]*W[(size_t)(k+1)*N + n];
      a2 += As[k+2]*W[(size_t)(k+2)*N + n];
      a3 += As[k+3]*W[(size_t)(k+3)*N + n];
    }
    float acc = (a0+a1)+(a2+a3) + (bias ? bias[n] : 0.0f);
    if (act == 1) acc = gelu_f(acc);
    C[(size_t)r*N + n] = acc;
  }
}

// ---------------- radial[h,i,j] ---------------------------------------------
__global__ __launch_bounds__(256) void k_radial(const float* __restrict__ d,
                                                const float* __restrict__ w,
                                                float* __restrict__ rad, int n){
  int gid = blockIdx.x*256 + threadIdx.x;
  int nn = n*n;
  int h = gid / nn; int rem = gid % nn;
  float dv = d[rem];
  float safe = fmaxf(dv, 1e-6f);
  float acc = 0.0f;
  for (int k = 0; k < 32; ++k){
    float nk = (float)(k+1);
    float basis = (dv > 1e-6f) ? (sinf(dv*nk)/safe) : nk;
    acc += basis * w[k*8 + h];
  }
  rad[gid] = acc;
}

// ------- kT transpose via LDS tiles: kT[((b*8+h)*64+d)][j] -----------------
// reads qk[(b*n+j)][512+h*64+d] coalesced along d; writes coalesced along j.
__global__ __launch_bounds__(256) void k_qkT2(const float* __restrict__ qk,
                                              float* __restrict__ kT, int n){
  __shared__ float tile[64][65];
  int tid = threadIdx.x;
  int bid = blockIdx.x;
  int ntj = n >> 6;
  int jt = bid % ntj; int h = (bid / ntj) & 7; int b = bid / (ntj*8);
  int j0 = jt*64;
  // load 64 j-rows x 64 d
  for (int it = 0; it < 16; ++it){
    int idx = it*256 + tid;
    int jr = idx >> 6, d = idx & 63;
    tile[jr][d] = qk[((size_t)(b*n + j0 + jr))*1024 + 512 + h*64 + d];
  }
  __syncthreads();
  // store 64 d-rows x 64 j
  for (int it = 0; it < 16; ++it){
    int idx = it*256 + tid;
    int dr = idx >> 6, j = idx & 63;
    kT[((size_t)((b*8 + h)*64 + dr))*n + j0 + j] = tile[j][dr];
  }
}

// ------- attention weights -> bf16 rows [bh][i][j], coalesced K reads ------
__global__ __launch_bounds__(256) void k_attn2(const float* __restrict__ qk,
                                               const float* __restrict__ kT,
                                               const float* __restrict__ rad,
                                               u16* __restrict__ kout, int n){
  extern __shared__ float sm[];   // qs[64] + red[8]
  float* qs = sm; float* red = sm + 64;
  int j = threadIdx.x;
  int bid = blockIdx.x; int i = bid % n; int h = (bid / n) & 7; int b = bid / (n*8);
  if (j < 64) qs[j] = qk[((size_t)(b*n + i))*1024 + h*64 + j];
  __syncthreads();
  const float* kcol = kT + ((size_t)((b*8 + h)*64))*n + j;
  float dot = 0.0f;
  #pragma unroll 8
  for (int d0 = 0; d0 < 64; ++d0) dot += qs[d0]*kcol[(size_t)d0*n];
  float s = dot * rad[((size_t)(h*n + i))*n + j];
  // block max: wave shuffle + tiny LDS cross-wave
  float m = s;
  #pragma unroll
  for (int off = 32; off; off >>= 1) m = fmaxf(m, __shfl_xor(m, off));
  int wv = j >> 6, nw = n >> 6;
  if ((j & 63) == 0) red[wv] = m;
  __syncthreads();
  m = red[0];
  for (int w = 1; w < nw; ++w) m = fmaxf(m, red[w]);
  float e = __builtin_amdgcn_exp2f((s - m)*1.44269504088896f);
  float t = e;
  #pragma unroll
  for (int off = 32; off; off >>= 1) t += __shfl_xor(t, off);
  if ((j & 63) == 0) red[4 + wv] = t;
  __syncthreads();
  t = 0.0f;
  for (int w = 0; w < nw; ++w) t += red[4 + w];
  kout[(size_t)bid*n + j] = f2bits(e / t);
}

// ======== k_v3: v-proj, j-major tiles, LDS-transposed output ===============
// M=512 hc, N=64 tokens {tok = j*256+m, j in [jt*64, jt*64+64), m fixed}, K=256.
// Output: vA[h][(c*256+m)][j]  (j fastest, coalesced 16B stores).
__global__ __launch_bounds__(256, 2) void k_v3(const u16* __restrict__ um,
                                               const u16* __restrict__ WvT,
                                               u16* __restrict__ vA,
                                               int b0, size_t bstr){
  __shared__ __align__(16) u16 T[512][72];   // 72 KB, row stride 144B (16-mult)
  int tid = threadIdx.x;
  int wave = tid>>6, lane = tid&63, quad = lane>>4, l15 = lane&15;
  int bid = blockIdx.x;
  int b = b0 + (bid >> 9);
  int rem = bid & 511;
  int m = rem & 255, jt = rem >> 8;
  const u16* umb = um + ((size_t)b*32768)*256;
  f32x4 acc[8][4];
  #pragma unroll
  for (int mt = 0; mt < 8; ++mt)
    #pragma unroll
    for (int nt = 0; nt < 4; ++nt) acc[mt][nt] = (f32x4){0.f,0.f,0.f,0.f};
  for (int ks = 0; ks < 8; ++ks){
    short8 bfr[4];
    #pragma unroll
    for (int nt = 0; nt < 4; ++nt){
      int j = jt*64 + nt*16 + l15;
      bfr[nt] = *(const short8*)(umb + ((size_t)j*256 + m)*256 + ks*32 + quad*8);
    }
    #pragma unroll
    for (int mt = 0; mt < 8; ++mt){
      short8 a = *(const short8*)(WvT + (size_t)((wave*8+mt)*16 + l15)*256 + ks*32 + quad*8);
      #pragma unroll
      for (int nt = 0; nt < 4; ++nt)
        acc[mt][nt] = __builtin_amdgcn_mfma_f32_16x16x32_bf16(a, bfr[nt], acc[mt][nt], 0, 0, 0);
    }
  }
  // C-tile -> LDS (transpose hc x j')
  #pragma unroll
  for (int mt = 0; mt < 8; ++mt){
    int hc0 = (wave*8+mt)*16 + quad*4;
    #pragma unroll
    for (int nt = 0; nt < 4; ++nt){
      int jp = nt*16 + l15;
      T[hc0+0][jp] = f2bits(acc[mt][nt][0]);
      T[hc0+1][jp] = f2bits(acc[mt][nt][1]);
      T[hc0+2][jp] = f2bits(acc[mt][nt][2]);
      T[hc0+3][jp] = f2bits(acc[mt][nt][3]);
    }
  }
  __syncthreads();
  // coalesced store: rows (h,c) of 64 j values (128B), 16B per lane
  u16* vAb = vA + (size_t)(b - b0)*bstr;
  for (int it = 0; it < 16; ++it){
    int idx = it*256 + tid;          // 4096 units of 8 u16
    int g = idx & 7, hc = idx >> 3;
    short8 v8 = *(const short8*)&T[hc][g*8];
    int h = hc >> 6, c = hc & 63;
    *(short8*)(vAb + (size_t)h*2097152 + ((size_t)c*256 + m)*128 + jt*64 + g*8) = v8;
  }
}

// ======== k_phi1c: C^T. M=(c,m) per block c fixed, N=i 128, K=j 128 ========
// A = contiguous vA rows [cm][j], B = ky rows. Out: phi[h][i][c*256+m] (as before)
__global__ __launch_bounds__(256) void k_phi1c(const u16* __restrict__ kyb,
                                               const u16* __restrict__ vA,
                                               u16* __restrict__ phi,
                                               int b0, size_t bstr){
  int tid = threadIdx.x;
  int wave = tid>>6, lane = tid&63, quad = lane>>4, l15 = lane&15;
  int bid = blockIdx.x;
  int b = b0 + (bid >> 9);
  int rem = bid & 511; int mblk = rem & 63, h = rem >> 6;
  int m0 = mblk*256;
  const u16* vAh = vA + (size_t)(b - b0)*bstr + (size_t)h*2097152;
  u16* phib = phi + (size_t)(b - b0)*bstr;
  const u16* kyh = kyb + (size_t)(b*8+h)*16384;
  f32x4 acc[4][8];
  #pragma unroll
  for (int mt = 0; mt < 4; ++mt)
    #pragma unroll
    for (int nt = 0; nt < 8; ++nt) acc[mt][nt] = (f32x4){0.f,0.f,0.f,0.f};
  for (int ks = 0; ks < 4; ++ks){
    short8 bfr[8];
    #pragma unroll
    for (int nt = 0; nt < 8; ++nt)
      bfr[nt] = *(const short8*)(kyh + (size_t)(nt*16 + l15)*128 + ks*32 + quad*8);
    #pragma unroll
    for (int mt = 0; mt < 4; ++mt){
      int cm = m0 + (wave*4+mt)*16 + l15;
      short8 a = *(const short8*)(vAh + (size_t)cm*128 + ks*32 + quad*8);
      #pragma unroll
      for (int nt = 0; nt < 8; ++nt)
        acc[mt][nt] = __builtin_amdgcn_mfma_f32_16x16x32_bf16(a, bfr[nt], acc[mt][nt], 0, 0, 0);
    }
  }
  #pragma unroll
  for (int mt = 0; mt < 4; ++mt){
    int cmr = m0 + (wave*4+mt)*16 + quad*4;
    #pragma unroll
    for (int nt = 0; nt < 8; ++nt){
      int i = nt*16 + l15;
      *(short4*)(phib + (size_t)h*2097152 + (size_t)i*16384 + cmr)
        = pack4(acc[mt][nt][0], acc[mt][nt][1], acc[mt][nt][2], acc[mt][nt][3]);
    }
  }
}

// ======== k_phi2b: M=(i,c) 8192, N=l 256, K=m 256 ==========================
__global__ __launch_bounds__(256) void k_phi2b(const u16* __restrict__ kxb,
                                               const u16* __restrict__ phi,
                                               u16* __restrict__ OUTt,
                                               int b0, size_t bstr){
  int tid = threadIdx.x;
  int wave = tid>>6, lane = tid&63, quad = lane>>4, l15 = lane&15;
  int bid = blockIdx.x;
  int b = b0 + (bid >> 9);
  int rem = bid & 511; int mblk = rem & 63, h = rem >> 6;
  int m0 = mblk*128;
  int mhalf = (wave&1)*4, nhalf = (wave>>1)*8;
  const u16* ph = phi + (size_t)(b - b0)*bstr + (size_t)h*2097152;
  u16* OUTb = OUTt + (size_t)(b - b0)*bstr;
  const u16* kxh = kxb + (size_t)(b*8+h)*65536;
  f32x4 acc[4][8];
  #pragma unroll
  for (int mt = 0; mt < 4; ++mt)
    #pragma unroll
    for (int nt = 0; nt < 8; ++nt) acc[mt][nt] = (f32x4){0.f,0.f,0.f,0.f};
  for (int ks = 0; ks < 8; ++ks){
    short8 bfr[8];
    #pragma unroll
    for (int nt = 0; nt < 8; ++nt)
      bfr[nt] = *(const short8*)(kxh + (size_t)((nhalf+nt)*16 + l15)*256 + ks*32 + quad*8);
    #pragma unroll
    for (int mt = 0; mt < 4; ++mt){
      int m2 = m0 + (mhalf+mt)*16 + l15;
      short8 a = *(const short8*)(ph + (size_t)m2*256 + ks*32 + quad*8);
      #pragma unroll
      for (int nt = 0; nt < 8; ++nt)
        acc[mt][nt] = __builtin_amdgcn_mfma_f32_16x16x32_bf16(a, bfr[nt], acc[mt][nt], 0, 0, 0);
    }
  }
  #pragma unroll
  for (int mt = 0; mt < 4; ++mt){
    int m2r = m0 + (mhalf+mt)*16 + quad*4;
    #pragma unroll
    for (int nt = 0; nt < 8; ++nt){
      int l = (nhalf+nt)*16 + l15;
      *(short4*)(OUTb + (size_t)h*2097152 + (size_t)l*8192 + m2r)
        = pack4(acc[mt][nt][0], acc[mt][nt][1], acc[mt][nt][2], acc[mt][nt][3]);
    }
  }
}

// ======== k_gnb: GroupNorm over 64-c groups, coalesced ======================
__global__ __launch_bounds__(256) void k_gnb(const u16* __restrict__ OUTt,
                                             u16* __restrict__ gn,
                                             int b0, size_t bstr){
  int tid = threadIdx.x;
  int bid = blockIdx.x;
  int bi = bid >> 11;
  int rem = bid & 2047; int l = rem & 255, h = rem >> 8;
  int i = tid >> 1, half = tid & 1;
  const u16* src = OUTt + (size_t)bi*bstr + (size_t)h*2097152 + (size_t)l*8192 + i*64 + half*32;
  float v[32]; float s1 = 0.f, s2 = 0.f;
  #pragma unroll
  for (int c4 = 0; c4 < 8; ++c4){
    short4 v4 = *(const short4*)(src + c4*4);
    v[c4*4+0] = bits2f((u16)v4.x); v[c4*4+1] = bits2f((u16)v4.y);
    v[c4*4+2] = bits2f((u16)v4.z); v[c4*4+3] = bits2f((u16)v4.w);
  }
  #pragma unroll
  for (int c = 0; c < 32; ++c){ s1 += v[c]; s2 += v[c]*v[c]; }
  s1 += __shfl_xor(s1, 1); s2 += __shfl_xor(s2, 1);
  float mean = s1*(1.0f/64.0f);
  float var = s2*(1.0f/64.0f) - mean*mean;
  float rstd = rsqrtf(var + 1e-6f);
  u16* dst = gn + (size_t)bi*bstr + ((size_t)(i*256 + l))*512 + h*64 + half*32;
  #pragma unroll
  for (int c4 = 0; c4 < 8; ++c4)
    *(short4*)(dst + c4*4) = pack4((v[c4*4+0]-mean)*rstd, (v[c4*4+1]-mean)*rstd,
                                   (v[c4*4+2]-mean)*rstd, (v[c4*4+3]-mean)*rstd);
}

// ======== k_mergeb: C^T. M=d 256, N=128 tokens, K=512 ======================
__global__ __launch_bounds__(256) void k_mergeb(const u16* __restrict__ gn,
                                                const u16* __restrict__ WmT,
                                                const float* __restrict__ biasm,
                                                const float* __restrict__ mod,
                                                const void* __restrict__ u,
                                                void* __restrict__ outv,
                                                const int* __restrict__ flag,
                                                int b0, size_t bstr){
  __shared__ float smg[256], sbb[256];
  int f = *flag;
  int tid = threadIdx.x;
  int bid = blockIdx.x;
  int b = b0 + (bid >> 8);
  int t0 = (bid & 255)*128;
  smg[tid] = mod[b*1536 + 512 + tid];
  sbb[tid] = biasm[tid];
  __syncthreads();
  int wave = tid>>6, lane = tid&63, quad = lane>>4, l15 = lane&15;
  const u16* gnb = gn + (size_t)(b - b0)*bstr;
  int nt0 = wave*2;
  f32x4 acc[16][2];
  #pragma unroll
  for (int mt = 0; mt < 16; ++mt){ acc[mt][0] = (f32x4){0.f,0.f,0.f,0.f}; acc[mt][1] = (f32x4){0.f,0.f,0.f,0.f}; }
  for (int ks = 0; ks < 16; ++ks){
    short8 bfr[2];
    #pragma unroll
    for (int nti = 0; nti < 2; ++nti){
      int tok = t0 + (nt0+nti)*16 + l15;
      bfr[nti] = *(const short8*)(gnb + (size_t)tok*512 + ks*32 + quad*8);
    }
    #pragma unroll
    for (int mt = 0; mt < 16; ++mt){
      short8 a = *(const short8*)(WmT + (size_t)(mt*16 + l15)*512 + ks*32 + quad*8);
      #pragma unroll
      for (int nti = 0; nti < 2; ++nti)
        acc[mt][nti] = __builtin_amdgcn_mfma_f32_16x16x32_bf16(a, bfr[nti], acc[mt][nti], 0, 0, 0);
    }
  }
  #pragma unroll
  for (int mt = 0; mt < 16; ++mt){
    int d0 = mt*16 + quad*4;
    #pragma unroll
    for (int nti = 0; nti < 2; ++nti){
      int tok = t0 + (nt0+nti)*16 + l15;
      size_t o = ((size_t)b*32768 + tok)*256 + d0;
      float r0,r1,r2,r3;
      if (f){
        short4 rv = *(const short4*)((const bf16*)u + o);
        r0 = bits2f((u16)rv.x); r1 = bits2f((u16)rv.y); r2 = bits2f((u16)rv.z); r3 = bits2f((u16)rv.w);
      } else {
        float4 rv = *(const float4*)((const float*)u + o);
        r0 = rv.x; r1 = rv.y; r2 = rv.z; r3 = rv.w;
      }
      float y0 = r0 + smg[d0+0]*(acc[mt][nti][0] + sbb[d0+0]);
      float y1 = r1 + smg[d0+1]*(acc[mt][nti][1] + sbb[d0+1]);
      float y2 = r2 + smg[d0+2]*(acc[mt][nti][2] + sbb[d0+2]);
      float y3 = r3 + smg[d0+3]*(acc[mt][nti][3] + sbb[d0+3]);
      if (f) *(short4*)((bf16*)outv + o) = pack4(y0,y1,y2,y3);
      else   *(float4*)((float*)outv + o) = (float4){y0,y1,y2,y3};
    }
  }
}

// ======== k_ffn5: LDS-staged weights, 2 token-sets/wave (32 tok/wave) ======
// 128 tokens/block, grid 1024. Each weight b128 read feeds 2 MFMAs -> LDS
// read instructions per token halve vs k_ffn4 (the binding constraint).
__global__ __launch_bounds__(256, 2) void k_ffn5(
    const float* __restrict__ mod,
    const u16* __restrict__ w1f,
    const float* __restrict__ b1c,
    const u16* __restrict__ w2f,
    const float* __restrict__ b2c,
    void* __restrict__ outv,
    const int* __restrict__ flag){
  __shared__ __align__(16) u16 wbuf[2][16384];   // 2 x 32KB
  __shared__ __align__(16) u16 hs[128][40];      // per-wave 32 rows x 32 (+8 pad)
  int f = *flag;
  int tid = threadIdx.x;
  int wave = tid>>6, lane = tid&63, quad = lane>>4, l15 = lane&15;
  int mrow = wave*32;
  int t0 = blockIdx.x*128;
  int bb = t0 >> 15;
  const float* modp = mod + bb*1536;

  // ---- stage chunk 0 into wbuf[0] (async; overlaps the LN below) ----
  {
    #pragma unroll
    for (int i = 0; i < 8; ++i){
      int seg = wave*8 + i;
      const u16* src = (seg < 16)
          ? (w1f + (size_t)seg*512 + lane*8)
          : (w2f + (size_t)(seg-16)*512 + lane*8);
      stage16(src, &wbuf[0][seg*512]);
    }
  }

  // ---- LN in registers, 2 token sets ----
  short8 afr[2][8];
  #pragma unroll
  for (int s = 0; s < 2; ++s){
    size_t rowbase = ((size_t)(t0 + mrow + s*16 + l15))*256;
    float s1 = 0.f, s2 = 0.f;
    #pragma unroll
    for (int ks = 0; ks < 8; ++ks){
      int c0 = ks*32 + quad*8;
      float v0,v1,v2,v3,v4,v5,v6,v7;
      if (f){
        short8 r = *(const short8*)((const bf16*)outv + rowbase + c0);
        afr[s][ks] = r;
        v0 = bits2f((u16)r[0]); v1 = bits2f((u16)r[1]); v2 = bits2f((u16)r[2]); v3 = bits2f((u16)r[3]);
        v4 = bits2f((u16)r[4]); v5 = bits2f((u16)r[5]); v6 = bits2f((u16)r[6]); v7 = bits2f((u16)r[7]);
      } else {
        float4 fa = *(const float4*)((const float*)outv + rowbase + c0);
        float4 fb = *(const float4*)((const float*)outv + rowbase + c0 + 4);
        v0=fa.x; v1=fa.y; v2=fa.z; v3=fa.w; v4=fb.x; v5=fb.y; v6=fb.z; v7=fb.w;
        afr[s][ks] = pack8(v0,v1,v2,v3,v4,v5,v6,v7);
      }
      s1 += v0+v1+v2+v3+v4+v5+v6+v7;
      s2 += v0*v0+v1*v1+v2*v2+v3*v3+v4*v4+v5*v5+v6*v6+v7*v7;
    }
    s1 += __shfl_xor(s1, 16); s1 += __shfl_xor(s1, 32);
    s2 += __shfl_xor(s2, 16); s2 += __shfl_xor(s2, 32);
    float mean = s1*(1.0f/256.0f);
    float var = s2*(1.0f/256.0f) - mean*mean;
    float rstd = rsqrtf(var + 1e-5f);
    #pragma unroll
    for (int ks = 0; ks < 8; ++ks){
      int c0 = ks*32 + quad*8;
      float4 sh0 = *(const float4*)&modp[768 + c0];
      float4 sh1 = *(const float4*)&modp[768 + c0 + 4];
      float4 sc0 = *(const float4*)&modp[1024 + c0];
      float4 sc1 = *(const float4*)&modp[1024 + c0 + 4];
      short8 r = afr[s][ks];
      float y0 = (bits2f((u16)r[0]) - mean)*rstd*(1.0f+sc0.x) + sh0.x;
      float y1 = (bits2f((u16)r[1]) - mean)*rstd*(1.0f+sc0.y) + sh0.y;
      float y2 = (bits2f((u16)r[2]) - mean)*rstd*(1.0f+sc0.z) + sh0.z;
      float y3 = (bits2f((u16)r[3]) - mean)*rstd*(1.0f+sc0.w) + sh0.w;
      float y4 = (bits2f((u16)r[4]) - mean)*rstd*(1.0f+sc1.x) + sh1.x;
      float y5 = (bits2f((u16)r[5]) - mean)*rstd*(1.0f+sc1.y) + sh1.y;
      float y6 = (bits2f((u16)r[6]) - mean)*rstd*(1.0f+sc1.z) + sh1.z;
      float y7 = (bits2f((u16)r[7]) - mean)*rstd*(1.0f+sc1.w) + sh1.w;
      afr[s][ks] = pack8(y0,y1,y2,y3,y4,y5,y6,y7);
    }
  }

  __syncthreads();   // chunk 0 staged + all waves ready

  // ---- main loop: 32 chunks of 32 hidden, double-buffered weights ----
  f32x4 acc2[2][16];
  #pragma unroll
  for (int s = 0; s < 2; ++s)
    #pragma unroll
    for (int nt = 0; nt < 16; ++nt) acc2[s][nt] = (f32x4){0.f,0.f,0.f,0.f};
  int buf = 0;
  #pragma unroll 1
  for (int c = 0; c < 32; ++c){
    if (c < 31){
      int cn = c + 1;
      #pragma unroll
      for (int i = 0; i < 8; ++i){
        int seg = wave*8 + i;
        const u16* src = (seg < 16)
            ? (w1f + (size_t)cn*8192 + (size_t)seg*512 + lane*8)
            : (w2f + (size_t)cn*8192 + (size_t)(seg-16)*512 + lane*8);
        stage16(src, &wbuf[buf^1][seg*512]);
      }
    }
    const u16* w1l = &wbuf[buf][0];
    const u16* w2l = &wbuf[buf][8192];
    // gemm1: 32 tok x 32 hid, K=256; each weight read feeds both sets
    f32x4 acc1[2][2];
    acc1[0][0] = (f32x4){0.f,0.f,0.f,0.f}; acc1[0][1] = (f32x4){0.f,0.f,0.f,0.f};
    acc1[1][0] = (f32x4){0.f,0.f,0.f,0.f}; acc1[1][1] = (f32x4){0.f,0.f,0.f,0.f};
    #pragma unroll
    for (int ks = 0; ks < 8; ++ks){
      #pragma unroll
      for (int nt2 = 0; nt2 < 2; ++nt2){
        short8 bfr = *(const short8*)(w1l + (nt2*8 + ks)*512 + lane*8);
        acc1[0][nt2] = __builtin_amdgcn_mfma_f32_16x16x32_bf16(afr[0][ks], bfr, acc1[0][nt2], 0, 0, 0);
        acc1[1][nt2] = __builtin_amdgcn_mfma_f32_16x16x32_bf16(afr[1][ks], bfr, acc1[1][nt2], 0, 0, 0);
      }
    }
    __builtin_amdgcn_sched_barrier(0);
    // gelu + transposed scalar writes to this wave's private hs rows
    #pragma unroll
    for (int nt2 = 0; nt2 < 2; ++nt2){
      int hid = nt2*16 + l15;
      float b1 = b1c[c*32 + hid];
      #pragma unroll
      for (int s = 0; s < 2; ++s)
        #pragma unroll
        for (int r = 0; r < 4; ++r)
          hs[mrow + s*16 + quad*4 + r][hid] = f2bits(gelu_fast(acc1[s][nt2][r] + b1));
    }
    __builtin_amdgcn_sched_barrier(0);
    asm volatile("s_waitcnt lgkmcnt(0)" ::: "memory");
    __builtin_amdgcn_sched_barrier(0);
    // gemm2: 32 tok x 256 out, K=32 for this chunk; weight reads shared
    short8 a2_0 = *(const short8*)&hs[mrow + l15][quad*8];
    short8 a2_1 = *(const short8*)&hs[mrow + 16 + l15][quad*8];
    #pragma unroll
    for (int nt = 0; nt < 16; ++nt){
      short8 bfr = *(const short8*)(w2l + nt*512 + lane*8);
      acc2[0][nt] = __builtin_amdgcn_mfma_f32_16x16x32_bf16(a2_0, bfr, acc2[0][nt], 0, 0, 0);
      acc2[1][nt] = __builtin_amdgcn_mfma_f32_16x16x32_bf16(a2_1, bfr, acc2[1][nt], 0, 0, 0);
    }
    __syncthreads();
    buf ^= 1;
  }

  // ---- epilogue: u2 = u1 + g*(y + b2), in place ----
  #pragma unroll
  for (int nt = 0; nt < 16; ++nt){
    int col = nt*16 + l15;
    float g = modp[1280 + col];
    float b2v = b2c[col];
    #pragma unroll
    for (int s = 0; s < 2; ++s)
      #pragma unroll
      for (int r = 0; r < 4; ++r){
        size_t o = ((size_t)(t0 + mrow + s*16 + quad*4 + r))*256 + col;
        float resid = f ? bits2f(((const u16*)outv)[o]) : ((const float*)outv)[o];
        float y = resid + g*(acc2[s][nt][r] + b2v);
        if (f) ((u16*)outv)[o] = f2bits(y);
        else   ((float*)outv)[o] = y;
      }
  }
}

extern "C" void kernel_launch(void* const* d_in, const int* in_sizes, int n_in,
                              void* d_out, int out_size, void* d_ws, size_t ws_size,
                              hipStream_t stream){
  (void)n_in; (void)out_size;

  char* p = (char*)d_ws;
  auto alloc = [&](size_t bytes)->void*{
    void* r = (void*)p; p += (bytes + 255) & ~(size_t)255; return r;
  };

  int* flag = (int*)alloc(4);
  float* cin[28];
  cin[0] = nullptr;
  for (int i = 1; i < 28; ++i) cin[i] = (float*)alloc((size_t)in_sizes[i]*4);

  float* mod  = (float*)alloc((size_t)4*1536*4);
  float* lw   = (float*)alloc((size_t)128*4);
  float* redx = (float*)alloc((size_t)4*256*256*4);
  float* redy = (float*)alloc((size_t)4*128*256*4);
  float* tx   = (float*)alloc((size_t)4*256*256*4);
  float* hx   = (float*)alloc((size_t)4*256*256*4);
  float* uxb  = (float*)alloc((size_t)4*256*128*4);
  float* ty   = (float*)alloc((size_t)4*128*256*4);
  float* hy   = (float*)alloc((size_t)4*128*256*4);
  float* uyb  = (float*)alloc((size_t)4*128*128*4);
  float* qkx  = (float*)alloc((size_t)4*256*1024*4);
  float* qky  = (float*)alloc((size_t)4*128*1024*4);
  float* kTx  = (float*)alloc((size_t)4*8*64*256*4);   // 2MB
  float* kTy  = (float*)alloc((size_t)4*8*64*128*4);   // 1MB
  float* radx = (float*)alloc((size_t)8*256*256*4);
  float* rady = (float*)alloc((size_t)8*128*128*4);
  u16* kxb = (u16*)alloc((size_t)32*256*256*2);
  u16* kyb = (u16*)alloc((size_t)32*128*128*2);
  u16* w1f = (u16*)alloc((size_t)256*1024*2);
  u16* w2f = (u16*)alloc((size_t)1024*256*2);
  u16* WvT = (u16*)alloc((size_t)512*256*2);
  u16* WmT = (u16*)alloc((size_t)256*512*2);
  u16* um  = (u16*)alloc((size_t)NTOK*256*2);          // 67 MB

  // slots: merged mode needs 4 b's live in both slots (268 MB); fall back to
  // the per-b serial chain when the workspace is too small.
  size_t used = (size_t)(p - (char*)d_ws);
  int merged = (ws_size > used) && ((ws_size - used) >= (size_t)8*SLOT_ELE*2 + 65536);
  size_t slotBytes = (merged ? 4 : 1) * SLOT_ELE * 2;
  u16* slotV = (u16*)alloc(slotBytes);
  u16* slotP = (u16*)alloc(slotBytes);

  const void* u = d_in[0];

  k_detect<<<1, 1, 0, stream>>>(d_in[3], flag);
  {
    CvtTab t;
    int cum = 0;
    for (int i = 1; i < 28; ++i){
      t.src[i-1] = d_in[i];
      t.dst[i-1] = cin[i];
      t.cum[i-1] = cum;
      cum += in_sizes[i];
    }
    t.cum[27] = cum;
    k_cvtall<<<2048, 256, 0, stream>>>(t, flag, cum);
  }
  k_wprep<<<1024, 256, 0, stream>>>(cin[24], w1f, 8, 1024, 256*1024);
  k_wprep2<<<1024, 256, 0, stream>>>(cin[26], w2f);
  k_wtrans<<<512, 256, 0, stream>>>(cin[7],  WvT, 256, 512);   // to_v_w
  k_wtrans<<<512, 256, 0, stream>>>(cin[22], WmT, 512, 256);   // merge_w

  k_mod<<<24, 256, 0, stream>>>(cin[4], cin[5], cin[6], mod);
  k_lw<<<1, 128, 0, stream>>>(cin[1], lw);
  k_um2<<<NTOK/64, 256, 0, stream>>>(u, mod, um, flag);
  k_redx<<<1024, 256, 0, stream>>>(um, lw, redx);
  k_redy<<<512, 256, 0, stream>>>(um, redy);
  // bottleneck chains, x+y fused per stage
  gemm_row2<<<1536, 256, 0, stream>>>(redx, cin[8],  nullptr,  tx,  256, 256,
                                      redy, cin[13], nullptr,  ty,  256, 256, 1024, 0);
  gemm_row2<<<1536, 256, 0, stream>>>(tx,   cin[9],  cin[10],  hx,  256, 256,
                                      ty,   cin[14], cin[15],  hy,  256, 256, 1024, 1);
  gemm_row2<<<1536, 256, 0, stream>>>(hx,   cin[11], cin[12],  uxb, 256, 128,
                                      hy,   cin[16], cin[17],  uyb, 256, 128, 1024, 0);
  gemm_row2<<<1536, 256, 0, stream>>>(uxb,  cin[18], nullptr,  qkx, 128, 1024,
                                      uyb,  cin[19], nullptr,  qky, 128, 1024, 1024, 0);
  k_radial<<<(8*256*256)/256, 256, 0, stream>>>(cin[3], cin[20], radx, 256);
  k_radial<<<(8*128*128)/256, 256, 0, stream>>>(cin[2], cin[21], rady, 128);
  k_qkT2<<<4*8*4, 256, 0, stream>>>(qkx, kTx, 256);
  k_qkT2<<<4*8*2, 256, 0, stream>>>(qky, kTy, 128);
  k_attn2<<<4*8*256, 256, (64+8)*4, stream>>>(qkx, kTx, radx, kxb, 256);
  k_attn2<<<4*8*128, 128, (64+8)*4, stream>>>(qky, kTy, rady, kyb, 128);

  if (merged){
    // all 4 batches in flight; slotV/slotP hold [b][...] with stride SLOT_ELE
    k_v3    <<<2048, 256, 0, stream>>>(um, WvT, slotV, 0, SLOT_ELE);    // vA
    k_phi1c <<<2048, 256, 0, stream>>>(kyb, slotV, slotP, 0, SLOT_ELE); // phi
    k_phi2b <<<2048, 256, 0, stream>>>(kxb, slotP, slotV, 0, SLOT_ELE); // vA dead
    k_gnb   <<<8192, 256, 0, stream>>>(slotV, slotP, 0, SLOT_ELE);      // phi dead
    k_mergeb<<<1024, 256, 0, stream>>>(slotP, WmT, cin[23], mod, u, d_out, flag, 0, SLOT_ELE);
  } else {
    for (int b = 0; b < 4; ++b){
      k_v3    <<<512, 256, 0, stream>>>(um, WvT, slotV, b, 0);
      k_phi1c <<<512, 256, 0, stream>>>(kyb, slotV, slotP, b, 0);
      k_phi2b <<<512, 256, 0, stream>>>(kxb, slotP, slotV, b, 0);
      k_gnb   <<<2048, 256, 0, stream>>>(slotV, slotP, b, 0);
      k_mergeb<<<256, 256, 0, stream>>>(slotP, WmT, cin[23], mod, u, d_out, flag, b, 0);
    }
  }
  k_ffn5<<<NTOK/128, 256, 0, stream>>>(mod, w1f, cin[25], w2f, cin[27], d_out, flag);
}